// Round 7
// baseline (157.662 us; speedup 1.0000x reference)
//
#include <hip/hip_runtime.h>
#include <hip/hip_bf16.h>

#define BATCH 4
#define SEQ   4096
#define EMB   1024
#define HD    64
#define N3    192
#define NSPLIT 8

typedef __attribute__((ext_vector_type(8)))  short short8;
typedef __attribute__((ext_vector_type(4)))  float floatx4;
typedef __attribute__((ext_vector_type(16))) float floatx16;
typedef unsigned long long ull;
typedef unsigned short us;

#define SSCALE 0.1803368801111204f   /* 0.125 * log2(e) */

static __device__ __forceinline__ us f2bf(float f) {
    unsigned int u = __float_as_uint(f);
    u += 0x7fffu + ((u >> 16) & 1u);
    return (us)(u >> 16);
}
static __device__ __forceinline__ float bf2f(us h) {
    return __uint_as_float((unsigned int)h << 16);
}
static __device__ __forceinline__ unsigned int cvtpk(float lo, float hi) {
    unsigned int r;
    asm("v_cvt_pk_bf16_f32 %0, %1, %2" : "=v"(r) : "v"(lo), "v"(hi));
    return r;
}
static __device__ __forceinline__ void gll16(const void* g, void* l) {
    __builtin_amdgcn_global_load_lds(
        (const __attribute__((address_space(1))) unsigned int*)(unsigned long long)g,
        (__attribute__((address_space(3))) unsigned int*)(unsigned int)(unsigned long long)l,
        16, 0, 0);
}

#define MFMA16(A, B, C) __builtin_amdgcn_mfma_f32_16x16x32_bf16(A, B, C, 0, 0, 0)
#define MFMA32(A, B, C) __builtin_amdgcn_mfma_f32_32x32x16_bf16(A, B, C, 0, 0, 0)

// ---------- Stage 0: W fp32 [1024][192] -> B-fragment-packed bf16 -------------
// wf[kb][cb][l][e] = bf16(w[kb*32 + (l>>4)*8 + e][cb*16 + (l&15)])
__global__ __launch_bounds__(256) void wt_prep(const float* __restrict__ w,
                                               us* __restrict__ wf)
{
    int t = blockIdx.x * 256 + threadIdx.x;   // 24576 = 32 kb x 12 cb x 64 l
    int l  = t & 63;
    int cb = (t >> 6) % 12;
    int kb = t / (64 * 12);
    int kbase = kb * 32 + (l >> 4) * 8;
    int n = cb * 16 + (l & 15);
    us e[8];
#pragma unroll
    for (int i = 0; i < 8; ++i)
        e[i] = f2bf(w[(size_t)(kbase + i) * N3 + n]);
    *(short8*)(wf + (size_t)t * 8) = *(short8*)e;
}

// ---------------- Stage 1: QKV projection -------------------------------------
// 256 blocks x 1024 thr (16 waves, 4M x 4N). M-tile 64 (halves W re-reads vs 32).
// X staged fp32 via global_load_lds (double-buffered K-chunks of 128), converted
// to bf16 at fragment-build time. W read as pre-packed coalesced fragments.
__global__ __launch_bounds__(1024, 4) void qkv_proj(
    const float* __restrict__ x, const us* __restrict__ wf,
    us* __restrict__ q, us* __restrict__ k, us* __restrict__ vt)
{
    const int tid = threadIdx.x;
    const int w   = tid >> 6;        // 0..15
    const int l   = tid & 63;
    const int ln  = l & 15;
    const int g   = l >> 4;
    const int wm  = w >> 2;          // 0..3 : 16-row block
    const int wn  = w & 3;           // 0..3 : 48-col strip
    const int row0 = blockIdx.x * 64;

    __shared__ __align__(16) char Xs[2][32768];   // [buf][64 rows][128 k] fp32, swizzled

    // linear LDS dest (wave-uniform base + lane*16), inverse-swizzled global src
    auto stage = [&](int c) {
#pragma unroll
        for (int i = 0; i < 2; ++i) {
            int unit = i * 1024 + tid;           // 2048 x 16B units
            int row  = unit >> 5;                // 0..63
            int su   = unit & 31;
            gll16(x + (size_t)(row0 + row) * EMB + c * 128 + ((su ^ (row & 7)) << 2),
                  Xs[c & 1] + unit * 16);
        }
    };

    stage(0);

    floatx4 acc[3];
#pragma unroll
    for (int ng = 0; ng < 3; ++ng) acc[ng] = (floatx4){0.f, 0.f, 0.f, 0.f};

    const int rowl = wm * 16 + ln;   // LDS row this lane reads (0..63)

    for (int c = 0; c < 8; ++c) {
        asm volatile("s_waitcnt vmcnt(0)" ::: "memory");   // stage(c) landed
        __builtin_amdgcn_sched_barrier(0);
        __syncthreads();

        // W fragments for this chunk: 12 coalesced 1KB wave-loads, issued
        // BEFORE stage(c+1) so waiting on them never drains the gll16 queue.
        short8 wfr[4][3];
#pragma unroll
        for (int ks = 0; ks < 4; ++ks)
#pragma unroll
            for (int ng = 0; ng < 3; ++ng)
                wfr[ks][ng] = *(const short8*)(wf +
                    ((size_t)((c * 4 + ks) * 12 + wn * 3 + ng) * 64 + l) * 8);
        asm volatile("" ::: "memory");           // keep W issue ahead of stage

        if (c < 7) stage(c + 1);

        const char* Bx = Xs[c & 1];
#pragma unroll
        for (int ks = 0; ks < 4; ++ks) {
            int ub = ks * 8 + g * 2;
            float4 a0 = *(const float4*)(Bx + rowl * 512 + (((ub + 0) ^ (rowl & 7)) << 4));
            float4 a1 = *(const float4*)(Bx + rowl * 512 + (((ub + 1) ^ (rowl & 7)) << 4));
            unsigned int p0 = cvtpk(a0.x, a0.y), p1 = cvtpk(a0.z, a0.w);
            unsigned int p2 = cvtpk(a1.x, a1.y), p3 = cvtpk(a1.z, a1.w);
            int4 av = {(int)p0, (int)p1, (int)p2, (int)p3};
            short8 af = *(short8*)&av;
#pragma unroll
            for (int ng = 0; ng < 3; ++ng)
                acc[ng] = MFMA16(af, wfr[ks][ng], acc[ng]);
        }
    }

    // epilogue: C/D layout col=lane&15, row=(lane>>4)*4+reg
#pragma unroll
    for (int ng = 0; ng < 3; ++ng) {
        int n = wn * 48 + ng * 16 + ln;
#pragma unroll
        for (int j = 0; j < 4; ++j) {
            int grow = row0 + wm * 16 + g * 4 + j;
            int b = grow >> 12;
            int s = grow & 4095;
            if (n < 64)
                q[(size_t)(b * SEQ + s) * HD + n] = f2bf(acc[ng][j] * SSCALE);
            else if (n < 128)
                k[(size_t)(b * SEQ + s) * HD + (n - 64)] = f2bf(acc[ng][j]);
            else
                vt[((size_t)b * HD + (n - 128)) * SEQ + s] = f2bf(acc[ng][j]);
        }
    }
}

// ---------------- Stage 2: flash attention, 32x32 swapped, KV-split x8 --------
// 512 blocks x 512 thr (8 waves). Block = 256 q-rows (halves KV re-reads),
// 8 key-tiles of 64 per split.
__global__ __launch_bounds__(512, 4) void attn(
    const us* __restrict__ qg, const us* __restrict__ kg,
    const us* __restrict__ vtg, us* __restrict__ pob, float* __restrict__ pml)
{
    const int tid = threadIdx.x;
    const int w   = tid >> 6;          // 0..7
    const int l   = tid & 63;
    const int qn  = l & 31;
    const int u   = l >> 5;
    const int bid = blockIdx.x;
    const int split = bid & 7;          // split == XCD -> KV split is L2-resident
    const int qt  = (bid >> 3) & 15;
    const int b   = bid >> 7;
    const int qr0 = qt * 256 + w * 32;

    __shared__ __align__(16) char LDSbuf[32768];   // 2 x (K 8KB + V 8KB); reused as Ts

    const us* kbase = kg  + (size_t)b * SEQ * HD;
    const us* vbase = vtg + (size_t)b * HD * SEQ;

    // Q fragments (B-operand of swapped QK^T): Q[q=qn][d = 16t + 8u + e]
    const us* qrow = qg + ((size_t)(b * SEQ) + qr0 + qn) * HD;
    short8 qf[4];
#pragma unroll
    for (int t = 0; t < 4; ++t) qf[t] = *(const short8*)(qrow + t * 16 + u * 8);

    const int ktbase = split * 8;

    // 512 thr: 1 gll16 for K + 1 for V per thread per tile
    auto stage = [&](int ktg, char* Kd, char* Vd) {
        int row = tid >> 3;                  // 0..63
        int c16 = (tid & 7) ^ (row & 7);
        gll16(kbase + (size_t)(ktg * 64 + row) * HD + c16 * 8, Kd + tid * 16);
        gll16(vbase + (size_t)row * SEQ + ktg * 64 + c16 * 8, Vd + tid * 16);
    };

    stage(ktbase, LDSbuf, LDSbuf + 8192);

    floatx16 o0 = {}, o1 = {};
    float m_run = -1e30f, l_run = 0.f;

    for (int kt = 0; kt < 8; ++kt) {
        asm volatile("s_waitcnt vmcnt(0)" ::: "memory");
        __syncthreads();
        char* Ks = LDSbuf + (kt & 1) * 16384;
        char* Vs = Ks + 8192;
        if (kt < 7) {
            char* Kn = LDSbuf + ((kt + 1) & 1) * 16384;
            stage(ktbase + kt + 1, Kn, Kn + 8192);
        }

        // S^T = K Q^T : A = K-frag (rows keys), B = Q-frag (cols q)
        floatx16 sa0 = {}, sa1 = {};
        __builtin_amdgcn_s_setprio(1);
#pragma unroll
        for (int t = 0; t < 4; ++t) {
            int r0 = qn, r1 = 32 + qn;
            short8 kf0 = *(const short8*)(Ks + r0 * 128 + ((32 * t + 16 * u) ^ ((r0 & 7) << 4)));
            short8 kf1 = *(const short8*)(Ks + r1 * 128 + ((32 * t + 16 * u) ^ ((r1 & 7) << 4)));
            sa0 = MFMA32(kf0, qf[t], sa0);
            sa1 = MFMA32(kf1, qf[t], sa1);
        }
        __builtin_amdgcn_s_setprio(0);

        // online softmax in exp2 domain; lane owns full row q = qn (partner l^32)
        // tree reduction (depth 5) instead of 31-deep serial chain
        float red[16];
#pragma unroll
        for (int r = 0; r < 16; ++r) red[r] = fmaxf(sa0[r], sa1[r]);
#pragma unroll
        for (int s = 8; s > 0; s >>= 1)
#pragma unroll
            for (int r = 0; r < s; ++r) red[r] = fmaxf(red[r], red[r + s]);
        float tm = fmaxf(red[0], __shfl_xor(red[0], 32));

        if (!__all(tm <= m_run + 8.f)) {       // T13 defer-max, THR=8
            float mn  = fmaxf(m_run, tm);
            float fac = exp2f(m_run - mn);
            m_run = mn;
            l_run *= fac;
#pragma unroll
            for (int r = 0; r < 16; ++r) { o0[r] *= fac; o1[r] *= fac; }
        }
#pragma unroll
        for (int r = 0; r < 16; ++r) { sa0[r] = exp2f(sa0[r] - m_run); }
#pragma unroll
        for (int r = 0; r < 16; ++r) { sa1[r] = exp2f(sa1[r] - m_run); }
        float sred[16];
#pragma unroll
        for (int r = 0; r < 16; ++r) sred[r] = sa0[r] + sa1[r];
#pragma unroll
        for (int s = 8; s > 0; s >>= 1)
#pragma unroll
            for (int r = 0; r < s; ++r) sred[r] += sred[r + s];
        l_run += sred[0] + __shfl_xor(sred[0], 32);

        // O^T += V^T P^T : per K-step s build P^T B-frag in-register (T12)
        __builtin_amdgcn_s_setprio(1);
#pragma unroll
        for (int s = 0; s < 4; ++s) {
            unsigned int A0, A1, B0, B1;
            if (s == 0) {
                A0 = cvtpk(sa0[0], sa0[1]);  A1 = cvtpk(sa0[2], sa0[3]);
                B0 = cvtpk(sa0[4], sa0[5]);  B1 = cvtpk(sa0[6], sa0[7]);
            } else if (s == 1) {
                A0 = cvtpk(sa0[8], sa0[9]);  A1 = cvtpk(sa0[10], sa0[11]);
                B0 = cvtpk(sa0[12], sa0[13]); B1 = cvtpk(sa0[14], sa0[15]);
            } else if (s == 2) {
                A0 = cvtpk(sa1[0], sa1[1]);  A1 = cvtpk(sa1[2], sa1[3]);
                B0 = cvtpk(sa1[4], sa1[5]);  B1 = cvtpk(sa1[6], sa1[7]);
            } else {
                A0 = cvtpk(sa1[8], sa1[9]);  A1 = cvtpk(sa1[10], sa1[11]);
                B0 = cvtpk(sa1[12], sa1[13]); B1 = cvtpk(sa1[14], sa1[15]);
            }
            asm("v_permlane32_swap_b32 %0, %1" : "+v"(A0), "+v"(B0));
            asm("v_permlane32_swap_b32 %0, %1" : "+v"(A1), "+v"(B1));
            int4 pbv = {(int)A0, (int)A1, (int)B0, (int)B1};
            short8 pb = *(short8*)&pbv;

            int rv0 = qn, rv1 = 32 + qn;
            short8 vf0 = *(const short8*)(Vs + rv0 * 128 + ((32 * s + 16 * u) ^ ((rv0 & 7) << 4)));
            short8 vf1 = *(const short8*)(Vs + rv1 * 128 + ((32 * s + 16 * u) ^ ((rv1 & 7) << 4)));
            o0 = MFMA32(vf0, pb, o0);
            o1 = MFMA32(vf1, pb, o1);
        }
        __builtin_amdgcn_s_setprio(0);
    }

    // epilogue: transpose O^T -> O via wave-private LDS scratch (8KB/wave),
    // 32KB available -> two rounds of 4 waves, barrier-separated.
    const size_t prow0 = (size_t)split * (BATCH * SEQ) + (size_t)b * SEQ + qr0;
    float* Ts = (float*)(LDSbuf + (w & 3) * 8192);   // [d 64][q 32]
#pragma unroll
    for (int round = 0; round < 2; ++round) {
        __syncthreads();
        if ((w >> 2) == round) {
#pragma unroll
            for (int r = 0; r < 16; ++r) {
                int d = (r & 3) + 8 * (r >> 2) + 4 * u;
                Ts[d * 32 + qn]        = o0[r];
                Ts[(d + 32) * 32 + qn] = o1[r];
            }
            // wave-local RAW; compiler inserts lgkmcnt
#pragma unroll
            for (int c = 0; c < 8; ++c) {
                float v0 = Ts[(u * 32 + c * 4 + 0) * 32 + qn];
                float v1 = Ts[(u * 32 + c * 4 + 1) * 32 + qn];
                float v2 = Ts[(u * 32 + c * 4 + 2) * 32 + qn];
                float v3 = Ts[(u * 32 + c * 4 + 3) * 32 + qn];
                ull pk =  (ull)f2bf(v0) | ((ull)f2bf(v1) << 16)
                       | ((ull)f2bf(v2) << 32) | ((ull)f2bf(v3) << 48);
                *(ull*)(pob + (prow0 + qn) * HD + u * 32 + c * 4) = pk;
            }
        }
    }
    if (l < 32) {
        pml[(prow0 + l) * 2 + 0] = m_run;
        pml[(prow0 + l) * 2 + 1] = l_run;
    }
}

// ---------------- Stage 3: recombine the 8 KV-splits --------------------------
__global__ __launch_bounds__(256) void recombine(
    const us* __restrict__ pob, const float* __restrict__ pml,
    float* __restrict__ out)
{
    int idx = blockIdx.x * 256 + threadIdx.x;   // 131072 = 16384 rows x 8 chunks
    int row = idx >> 3;
    int c8  = idx & 7;

    float m[NSPLIT], lv[NSPLIT];
#pragma unroll
    for (int i = 0; i < NSPLIT; ++i) {
        m[i]  = pml[((size_t)i * (BATCH * SEQ) + row) * 2 + 0];
        lv[i] = pml[((size_t)i * (BATCH * SEQ) + row) * 2 + 1];
    }
    float M = m[0];
#pragma unroll
    for (int i = 1; i < NSPLIT; ++i) M = fmaxf(M, m[i]);
    float wt[NSPLIT], denom = 0.f;
#pragma unroll
    for (int i = 0; i < NSPLIT; ++i) { wt[i] = exp2f(m[i] - M); denom += wt[i] * lv[i]; }
    float inv = 1.0f / denom;

    float acc[8];
#pragma unroll
    for (int e = 0; e < 8; ++e) acc[e] = 0.f;
#pragma unroll
    for (int i = 0; i < NSPLIT; ++i) {
        short8 v = *(const short8*)(pob + ((size_t)i * (BATCH * SEQ) + row) * HD + c8 * 8);
#pragma unroll
        for (int e = 0; e < 8; ++e) acc[e] += wt[i] * bf2f((us)v[e]);
    }
    float4 r0 = {acc[0] * inv, acc[1] * inv, acc[2] * inv, acc[3] * inv};
    float4 r1 = {acc[4] * inv, acc[5] * inv, acc[6] * inv, acc[7] * inv};
    *(float4*)(out + (size_t)row * HD + c8 * 8)     = r0;
    *(float4*)(out + (size_t)row * HD + c8 * 8 + 4) = r1;
}

extern "C" void kernel_launch(void* const* d_in, const int* in_sizes, int n_in,
                              void* d_out, int out_size, void* d_ws, size_t ws_size,
                              hipStream_t stream) {
    (void)in_sizes; (void)n_in; (void)out_size; (void)ws_size;
    const float* x = (const float*)d_in[0];
    const float* w = (const float*)d_in[1];
    float* out = (float*)d_out;

    const size_t QE = (size_t)BATCH * SEQ * HD;       // 1048576
    us* q   = (us*)d_ws;
    us* k   = q + QE;
    us* vt  = k + QE;
    us* wfb = vt + QE;
    us* pob = wfb + (size_t)N3 * EMB;                 // 8 x 16384 x 64 bf16
    float* pml = (float*)(pob + (size_t)NSPLIT * BATCH * SEQ * HD);

    wt_prep  <<<dim3(96),   dim3(256),  0, stream>>>(w, wfb);
    qkv_proj <<<dim3(256),  dim3(1024), 0, stream>>>(x, wfb, q, k, vt);
    attn     <<<dim3(512),  dim3(512),  0, stream>>>(q, k, vt, pob, pml);
    recombine<<<dim3(512),  dim3(256),  0, stream>>>(pob, pml, out);
}

// Round 8
// 149.044 us; speedup vs baseline: 1.0578x; 1.0578x over previous
//
#include <hip/hip_runtime.h>
#include <hip/hip_bf16.h>

#define BATCH 4
#define SEQ   4096
#define EMB   1024
#define HD    64
#define N3    192
#define NSPLIT 8

typedef __attribute__((ext_vector_type(8)))  short short8;
typedef __attribute__((ext_vector_type(4)))  float floatx4;
typedef __attribute__((ext_vector_type(16))) float floatx16;
typedef unsigned long long ull;
typedef unsigned short us;

#define SSCALE 0.1803368801111204f   /* 0.125 * log2(e) */

static __device__ __forceinline__ us f2bf(float f) {
    unsigned int u = __float_as_uint(f);
    u += 0x7fffu + ((u >> 16) & 1u);
    return (us)(u >> 16);
}
static __device__ __forceinline__ float bf2f(us h) {
    return __uint_as_float((unsigned int)h << 16);
}
static __device__ __forceinline__ unsigned int cvtpk(float lo, float hi) {
    unsigned int r;
    asm("v_cvt_pk_bf16_f32 %0, %1, %2" : "=v"(r) : "v"(lo), "v"(hi));
    return r;
}
static __device__ __forceinline__ void gll16(const void* g, void* l) {
    __builtin_amdgcn_global_load_lds(
        (const __attribute__((address_space(1))) unsigned int*)(unsigned long long)g,
        (__attribute__((address_space(3))) unsigned int*)(unsigned int)(unsigned long long)l,
        16, 0, 0);
}

#define MFMA16(A, B, C) __builtin_amdgcn_mfma_f32_16x16x32_bf16(A, B, C, 0, 0, 0)
#define MFMA32(A, B, C) __builtin_amdgcn_mfma_f32_32x32x16_bf16(A, B, C, 0, 0, 0)

// ---------- Stage 0: W fp32 [1024][192] -> B-fragment-packed bf16 -------------
// wf[kb][cb][l][e] = bf16(w[kb*32 + (l>>4)*8 + e][cb*16 + (l&15)])
__global__ __launch_bounds__(256) void wt_prep(const float* __restrict__ w,
                                               us* __restrict__ wf)
{
    int t = blockIdx.x * 256 + threadIdx.x;   // 24576 = 32 kb x 12 cb x 64 l
    int l  = t & 63;
    int cb = (t >> 6) % 12;
    int kb = t / (64 * 12);
    int kbase = kb * 32 + (l >> 4) * 8;
    int n = cb * 16 + (l & 15);
    us e[8];
#pragma unroll
    for (int i = 0; i < 8; ++i)
        e[i] = f2bf(w[(size_t)(kbase + i) * N3 + n]);
    *(short8*)(wf + (size_t)t * 8) = *(short8*)e;
}

// ---------------- Stage 1: QKV projection -------------------------------------
// 512 blocks x 512 thr (8 waves, 2M x 4N), M-tile 32, 2 blocks/CU.
// X staged fp32 via global_load_lds, TRIPLE-buffered K-chunks of 128 with
// depth-2 prefetch and counted vmcnt (never drain to 0 mid-loop).
__global__ __launch_bounds__(512, 4) void qkv_proj(
    const float* __restrict__ x, const us* __restrict__ wf,
    us* __restrict__ q, us* __restrict__ k, us* __restrict__ vt)
{
    const int tid = threadIdx.x;
    const int w   = tid >> 6;
    const int l   = tid & 63;
    const int ln  = l & 15;
    const int g   = l >> 4;
    const int wm  = w >> 2;          // 0..1 : row half
    const int wn  = w & 3;           // 0..3 : 48-col strip
    const int row0 = blockIdx.x * 32;

    __shared__ __align__(16) char Xs[3][16384];   // [buf][32 rows][128 k] fp32, swizzled

    const int srow  = tid >> 5;      // 0..15
    const int sunit = tid & 31;      // 16B unit within row

    // linear LDS dest (wave-uniform base + lane*16), inverse-swizzled global src
    auto stage = [&](int c) {
        char* dst = Xs[c % 3];
#pragma unroll
        for (int i = 0; i < 2; ++i) {
            int row = i * 16 + srow;
            gll16(x + (size_t)(row0 + row) * EMB + c * 128 + ((sunit ^ (row & 7)) << 2),
                  dst + i * 8192 + tid * 16);
        }
    };

    stage(0);
    stage(1);

    floatx4 acc[3];
#pragma unroll
    for (int ng = 0; ng < 3; ++ng) acc[ng] = (floatx4){0.f, 0.f, 0.f, 0.f};

    const int rowl = wm * 16 + ln;   // LDS row this lane reads (0..31)

    for (int c = 0; c < 8; ++c) {
        // counted drain: stage(c) has >=2 younger loads in the FIFO except at c=7
        if (c < 7) asm volatile("s_waitcnt vmcnt(2)" ::: "memory");
        else       asm volatile("s_waitcnt vmcnt(0)" ::: "memory");
        __builtin_amdgcn_sched_barrier(0);
        __syncthreads();

        // W fragments for this chunk: 12 coalesced 1KB wave-loads, issued
        // BEFORE stage(c+2) so waiting on them keeps the newest stage in flight.
        short8 wfr[4][3];
#pragma unroll
        for (int ks = 0; ks < 4; ++ks)
#pragma unroll
            for (int ng = 0; ng < 3; ++ng)
                wfr[ks][ng] = *(const short8*)(wf +
                    ((size_t)((c * 4 + ks) * 12 + wn * 3 + ng) * 64 + l) * 8);
        asm volatile("" ::: "memory");           // keep W issue ahead of stage

        if (c < 6) stage(c + 2);

        const char* Bx = Xs[c % 3];
#pragma unroll
        for (int ks = 0; ks < 4; ++ks) {
            int ub = ks * 8 + g * 2;
            float4 a0 = *(const float4*)(Bx + rowl * 512 + (((ub + 0) ^ (rowl & 7)) << 4));
            float4 a1 = *(const float4*)(Bx + rowl * 512 + (((ub + 1) ^ (rowl & 7)) << 4));
            unsigned int p0 = cvtpk(a0.x, a0.y), p1 = cvtpk(a0.z, a0.w);
            unsigned int p2 = cvtpk(a1.x, a1.y), p3 = cvtpk(a1.z, a1.w);
            int4 av = {(int)p0, (int)p1, (int)p2, (int)p3};
            short8 af = *(short8*)&av;
#pragma unroll
            for (int ng = 0; ng < 3; ++ng)
                acc[ng] = MFMA16(af, wfr[ks][ng], acc[ng]);
        }
    }

    // epilogue: C/D layout col=lane&15, row=(lane>>4)*4+reg
#pragma unroll
    for (int ng = 0; ng < 3; ++ng) {
        int n = wn * 48 + ng * 16 + ln;
#pragma unroll
        for (int j = 0; j < 4; ++j) {
            int grow = row0 + wm * 16 + g * 4 + j;
            int b = grow >> 12;
            int s = grow & 4095;
            if (n < 64)
                q[(size_t)(b * SEQ + s) * HD + n] = f2bf(acc[ng][j] * SSCALE);
            else if (n < 128)
                k[(size_t)(b * SEQ + s) * HD + (n - 64)] = f2bf(acc[ng][j]);
            else
                vt[((size_t)b * HD + (n - 128)) * SEQ + s] = f2bf(acc[ng][j]);
        }
    }
}

// ---------------- Stage 2: flash attention, 32x32 swapped, KV-split x8 --------
// 512 blocks x 512 thr (8 waves). Block = 256 q-rows, 8 key-tiles of 64 per
// split. TRIPLE-buffered K/V tiles with depth-2 prefetch + counted vmcnt.
__global__ __launch_bounds__(512, 4) void attn(
    const us* __restrict__ qg, const us* __restrict__ kg,
    const us* __restrict__ vtg, us* __restrict__ pob, float* __restrict__ pml)
{
    const int tid = threadIdx.x;
    const int w   = tid >> 6;          // 0..7
    const int l   = tid & 63;
    const int qn  = l & 31;
    const int u   = l >> 5;
    const int bid = blockIdx.x;
    const int split = bid & 7;          // split == XCD -> KV split is L2-resident
    const int qt  = (bid >> 3) & 15;
    const int b   = bid >> 7;
    const int qr0 = qt * 256 + w * 32;

    __shared__ __align__(16) char LDSbuf[49152];   // 3 x (K 8KB + V 8KB); Ts reuse

    const us* kbase = kg  + (size_t)b * SEQ * HD;
    const us* vbase = vtg + (size_t)b * HD * SEQ;

    const int ktbase = split * 8;

    // 512 thr: 1 gll16 for K + 1 for V per thread per tile
    auto stage = [&](int ktg, int buf) {
        char* Kd = LDSbuf + buf * 16384;
        int row = tid >> 3;                  // 0..63
        int c16 = (tid & 7) ^ (row & 7);
        gll16(kbase + (size_t)(ktg * 64 + row) * HD + c16 * 8, Kd + tid * 16);
        gll16(vbase + (size_t)row * SEQ + ktg * 64 + c16 * 8, Kd + 8192 + tid * 16);
    };

    stage(ktbase + 0, 0);
    stage(ktbase + 1, 1);

    // Q fragments (B-operand of swapped QK^T): Q[q=qn][d = 16t + 8u + e]
    const us* qrow = qg + ((size_t)(b * SEQ) + qr0 + qn) * HD;
    short8 qf[4];
#pragma unroll
    for (int t = 0; t < 4; ++t) qf[t] = *(const short8*)(qrow + t * 16 + u * 8);

    floatx16 o0 = {}, o1 = {};
    float m_run = -1e30f, l_run = 0.f;

    for (int kt = 0; kt < 8; ++kt) {
        if (kt < 7) asm volatile("s_waitcnt vmcnt(2)" ::: "memory");
        else        asm volatile("s_waitcnt vmcnt(0)" ::: "memory");
        __builtin_amdgcn_sched_barrier(0);
        __syncthreads();
        if (kt < 6) stage(ktbase + kt + 2, (kt + 2) % 3);
        char* Ks = LDSbuf + (kt % 3) * 16384;
        char* Vs = Ks + 8192;

        // S^T = K Q^T : A = K-frag (rows keys), B = Q-frag (cols q)
        floatx16 sa0 = {}, sa1 = {};
        __builtin_amdgcn_s_setprio(1);
#pragma unroll
        for (int t = 0; t < 4; ++t) {
            int r0 = qn, r1 = 32 + qn;
            short8 kf0 = *(const short8*)(Ks + r0 * 128 + ((32 * t + 16 * u) ^ ((r0 & 7) << 4)));
            short8 kf1 = *(const short8*)(Ks + r1 * 128 + ((32 * t + 16 * u) ^ ((r1 & 7) << 4)));
            sa0 = MFMA32(kf0, qf[t], sa0);
            sa1 = MFMA32(kf1, qf[t], sa1);
        }
        __builtin_amdgcn_s_setprio(0);

        // online softmax in exp2 domain; lane owns full row q = qn (partner l^32)
        // tree reduction (depth 5) instead of 31-deep serial chain
        float red[16];
#pragma unroll
        for (int r = 0; r < 16; ++r) red[r] = fmaxf(sa0[r], sa1[r]);
#pragma unroll
        for (int s = 8; s > 0; s >>= 1)
#pragma unroll
            for (int r = 0; r < s; ++r) red[r] = fmaxf(red[r], red[r + s]);
        float tm = fmaxf(red[0], __shfl_xor(red[0], 32));

        if (!__all(tm <= m_run + 8.f)) {       // T13 defer-max, THR=8
            float mn  = fmaxf(m_run, tm);
            float fac = exp2f(m_run - mn);
            m_run = mn;
            l_run *= fac;
#pragma unroll
            for (int r = 0; r < 16; ++r) { o0[r] *= fac; o1[r] *= fac; }
        }
#pragma unroll
        for (int r = 0; r < 16; ++r) { sa0[r] = exp2f(sa0[r] - m_run); }
#pragma unroll
        for (int r = 0; r < 16; ++r) { sa1[r] = exp2f(sa1[r] - m_run); }
        float sred[16];
#pragma unroll
        for (int r = 0; r < 16; ++r) sred[r] = sa0[r] + sa1[r];
#pragma unroll
        for (int s = 8; s > 0; s >>= 1)
#pragma unroll
            for (int r = 0; r < s; ++r) sred[r] += sred[r + s];
        l_run += sred[0] + __shfl_xor(sred[0], 32);

        // O^T += V^T P^T : per K-step s build P^T B-frag in-register (T12)
        __builtin_amdgcn_s_setprio(1);
#pragma unroll
        for (int s = 0; s < 4; ++s) {
            unsigned int A0, A1, B0, B1;
            if (s == 0) {
                A0 = cvtpk(sa0[0], sa0[1]);  A1 = cvtpk(sa0[2], sa0[3]);
                B0 = cvtpk(sa0[4], sa0[5]);  B1 = cvtpk(sa0[6], sa0[7]);
            } else if (s == 1) {
                A0 = cvtpk(sa0[8], sa0[9]);  A1 = cvtpk(sa0[10], sa0[11]);
                B0 = cvtpk(sa0[12], sa0[13]); B1 = cvtpk(sa0[14], sa0[15]);
            } else if (s == 2) {
                A0 = cvtpk(sa1[0], sa1[1]);  A1 = cvtpk(sa1[2], sa1[3]);
                B0 = cvtpk(sa1[4], sa1[5]);  B1 = cvtpk(sa1[6], sa1[7]);
            } else {
                A0 = cvtpk(sa1[8], sa1[9]);  A1 = cvtpk(sa1[10], sa1[11]);
                B0 = cvtpk(sa1[12], sa1[13]); B1 = cvtpk(sa1[14], sa1[15]);
            }
            asm("v_permlane32_swap_b32 %0, %1" : "+v"(A0), "+v"(B0));
            asm("v_permlane32_swap_b32 %0, %1" : "+v"(A1), "+v"(B1));
            int4 pbv = {(int)A0, (int)A1, (int)B0, (int)B1};
            short8 pb = *(short8*)&pbv;

            int rv0 = qn, rv1 = 32 + qn;
            short8 vf0 = *(const short8*)(Vs + rv0 * 128 + ((32 * s + 16 * u) ^ ((rv0 & 7) << 4)));
            short8 vf1 = *(const short8*)(Vs + rv1 * 128 + ((32 * s + 16 * u) ^ ((rv1 & 7) << 4)));
            o0 = MFMA32(vf0, pb, o0);
            o1 = MFMA32(vf1, pb, o1);
        }
        __builtin_amdgcn_s_setprio(0);
    }

    // epilogue: transpose O^T -> O via wave-private LDS scratch (8KB/wave),
    // two rounds of 4 waves, barrier-separated (uses first 32KB of LDSbuf).
    const size_t prow0 = (size_t)split * (BATCH * SEQ) + (size_t)b * SEQ + qr0;
    float* Ts = (float*)(LDSbuf + (w & 3) * 8192);   // [d 64][q 32]
#pragma unroll
    for (int round = 0; round < 2; ++round) {
        __syncthreads();
        if ((w >> 2) == round) {
#pragma unroll
            for (int r = 0; r < 16; ++r) {
                int d = (r & 3) + 8 * (r >> 2) + 4 * u;
                Ts[d * 32 + qn]        = o0[r];
                Ts[(d + 32) * 32 + qn] = o1[r];
            }
            // wave-local RAW; compiler inserts lgkmcnt
#pragma unroll
            for (int c = 0; c < 8; ++c) {
                float v0 = Ts[(u * 32 + c * 4 + 0) * 32 + qn];
                float v1 = Ts[(u * 32 + c * 4 + 1) * 32 + qn];
                float v2 = Ts[(u * 32 + c * 4 + 2) * 32 + qn];
                float v3 = Ts[(u * 32 + c * 4 + 3) * 32 + qn];
                ull pk =  (ull)f2bf(v0) | ((ull)f2bf(v1) << 16)
                       | ((ull)f2bf(v2) << 32) | ((ull)f2bf(v3) << 48);
                *(ull*)(pob + (prow0 + qn) * HD + u * 32 + c * 4) = pk;
            }
        }
    }
    if (l < 32) {
        pml[(prow0 + l) * 2 + 0] = m_run;
        pml[(prow0 + l) * 2 + 1] = l_run;
    }
}

// ---------------- Stage 3: recombine the 8 KV-splits --------------------------
__global__ __launch_bounds__(256) void recombine(
    const us* __restrict__ pob, const float* __restrict__ pml,
    float* __restrict__ out)
{
    int idx = blockIdx.x * 256 + threadIdx.x;   // 131072 = 16384 rows x 8 chunks
    int row = idx >> 3;
    int c8  = idx & 7;

    float m[NSPLIT], lv[NSPLIT];
#pragma unroll
    for (int i = 0; i < NSPLIT; ++i) {
        m[i]  = pml[((size_t)i * (BATCH * SEQ) + row) * 2 + 0];
        lv[i] = pml[((size_t)i * (BATCH * SEQ) + row) * 2 + 1];
    }
    float M = m[0];
#pragma unroll
    for (int i = 1; i < NSPLIT; ++i) M = fmaxf(M, m[i]);
    float wt[NSPLIT], denom = 0.f;
#pragma unroll
    for (int i = 0; i < NSPLIT; ++i) { wt[i] = exp2f(m[i] - M); denom += wt[i] * lv[i]; }
    float inv = 1.0f / denom;

    float acc[8];
#pragma unroll
    for (int e = 0; e < 8; ++e) acc[e] = 0.f;
#pragma unroll
    for (int i = 0; i < NSPLIT; ++i) {
        short8 v = *(const short8*)(pob + ((size_t)i * (BATCH * SEQ) + row) * HD + c8 * 8);
#pragma unroll
        for (int e = 0; e < 8; ++e) acc[e] += wt[i] * bf2f((us)v[e]);
    }
    float4 r0 = {acc[0] * inv, acc[1] * inv, acc[2] * inv, acc[3] * inv};
    float4 r1 = {acc[4] * inv, acc[5] * inv, acc[6] * inv, acc[7] * inv};
    *(float4*)(out + (size_t)row * HD + c8 * 8)     = r0;
    *(float4*)(out + (size_t)row * HD + c8 * 8 + 4) = r1;
}

extern "C" void kernel_launch(void* const* d_in, const int* in_sizes, int n_in,
                              void* d_out, int out_size, void* d_ws, size_t ws_size,
                              hipStream_t stream) {
    (void)in_sizes; (void)n_in; (void)out_size; (void)ws_size;
    const float* x = (const float*)d_in[0];
    const float* w = (const float*)d_in[1];
    float* out = (float*)d_out;

    const size_t QE = (size_t)BATCH * SEQ * HD;       // 1048576
    us* q   = (us*)d_ws;
    us* k   = q + QE;
    us* vt  = k + QE;
    us* wfb = vt + QE;
    us* pob = wfb + (size_t)N3 * EMB;                 // 8 x 16384 x 64 bf16
    float* pml = (float*)(pob + (size_t)NSPLIT * BATCH * SEQ * HD);

    wt_prep  <<<dim3(96),   dim3(256), 0, stream>>>(w, wfb);
    qkv_proj <<<dim3(512),  dim3(512), 0, stream>>>(x, wfb, q, k, vt);
    attn     <<<dim3(512),  dim3(512), 0, stream>>>(q, k, vt, pob, pml);
    recombine<<<dim3(512),  dim3(256), 0, stream>>>(pob, pml, out);
}